// Round 2
// baseline (745.582 us; speedup 1.0000x reference)
//
#include <hip/hip_runtime.h>

#define NN 131072
#define BB 32

struct LevelParams {
  const float* u[12];
  int t_off[12];   // float offsets into workspace
  int r[12];
  int rpad[12];
  int lb[12];      // log2(bsz); bsz = 2^(16-level)
};

// ---------------- t-pass: t[seg][n][j] = sum_{s in seg} U[s][j] * x[n][s] --------
// grid: 12 levels * 128 chunks (1024 rows each), 256 threads. NO global atomics:
// cross-split combine via LDS tree; levels 0..6 write per-chunk partials
// (reduced by reduce_kernel), levels 7..11 write t directly (unique writer).
__global__ __launch_bounds__(256, 3)
void tpass_kernel(const float* __restrict__ x, float* __restrict__ t,
                  float* __restrict__ part, LevelParams P) {
  __shared__ float xT[128 * 36];   // [s][n], padded
  __shared__ float Ut[128 * 64];   // [s][rpad]; reused as 4x2048 reduction scratch

  const int bid = blockIdx.x;
  const int l = bid >> 7;
  const int chunk = bid & 127;
  const int tid = threadIdx.x;

  const float* __restrict__ u = P.u[l];
  const int r = P.r[l];
  const int rpad = P.rpad[l];
  const int lb = P.lb[l];
  float* __restrict__ tl = t + P.t_off[l];

  const int G = rpad >> 3;           // active j-groups
  const int split = tid >> 5;        // 0..7 : 16-row slice within 128-row window
  const int lane32 = tid & 31;
  const int n0 = (lane32 >> 3) << 3; // 0,8,16,24
  const int jg = lane32 & 7;
  const int j0 = jg << 3;
  const bool active = (jg < G);

  const int lg = (lb >= 7) ? 3 : (lb - 4);  // log2(splits per segment group)
  const int gsz = 1 << lg;

  float acc[8][8];
  #pragma unroll
  for (int a = 0; a < 8; a++)
    #pragma unroll
    for (int b = 0; b < 8; b++) acc[a][b] = 0.f;

  const int Rc = chunk << 10;
  const int r4 = rpad >> 2;
  const int uslots = 32 * rpad;      // (128*rpad)/4 float4 slots

  for (int sub = 0; sub < 8; sub++) {
    const int s0 = Rc + (sub << 7);
    // stage x transposed: xT[ss][n]
    #pragma unroll
    for (int rep = 0; rep < 16; rep++) {
      int idx = rep * 256 + tid;
      int ss = idx & 127;
      int n = idx >> 7;
      xT[ss * 36 + n] = x[n * NN + s0 + ss];
    }
    // stage U rows (zero-pad j>=r)
    for (int slot = tid; slot < uslots; slot += 256) {
      int row = slot / r4;
      int c4 = slot - row * r4;
      int j = c4 << 2;
      float4 v;
      if (j < r) v = *(const float4*)&u[(s0 + row) * r + j];
      else       v = make_float4(0.f, 0.f, 0.f, 0.f);
      *(float4*)&Ut[row * rpad + j] = v;
    }
    __syncthreads();

    if (active) {
      const int sl0 = split << 4;
      #pragma unroll 4
      for (int ss = 0; ss < 16; ss++) {
        const int sl = sl0 + ss;
        float4 xa = *(const float4*)&xT[sl * 36 + n0];
        float4 xb = *(const float4*)&xT[sl * 36 + n0 + 4];
        float4 ua = *(const float4*)&Ut[sl * rpad + j0];
        float4 ub = *(const float4*)&Ut[sl * rpad + j0 + 4];
        float xs[8] = {xa.x, xa.y, xa.z, xa.w, xb.x, xb.y, xb.z, xb.w};
        float us[8] = {ua.x, ua.y, ua.z, ua.w, ub.x, ub.y, ub.z, ub.w};
        #pragma unroll
        for (int a = 0; a < 8; a++)
          #pragma unroll
          for (int b = 0; b < 8; b++)
            acc[a][b] += xs[a] * us[b];
      }
    }

    // block-uniform flush: end of chunk, or the 128-row window ends a segment
    const bool fl = (sub == 7) || (((s0 + 128) >> lb) != (s0 >> lb));
    if (fl) {
      __syncthreads();   // all compute reads of Ut done before reusing as scratch
      // tree-reduce across the gsz splits that share each segment
      for (int h = gsz >> 1; h >= 1; h >>= 1) {
        const int sig = split & (gsz - 1);
        if (active && sig >= h && sig < (h << 1)) {
          int rid = split - h;                         // reader split id
          int slot = (rid >> lg) * h + (rid & (gsz - 1));  // 0..3
          float* dst = Ut + slot * 2048 + lane32;      // [(a*8+b)][lane32]
          #pragma unroll
          for (int a = 0; a < 8; a++)
            #pragma unroll
            for (int b = 0; b < 8; b++)
              dst[(a * 8 + b) * 32] = acc[a][b];
        }
        __syncthreads();
        if (active && (split & (gsz - 1)) < h) {
          int slot = (split >> lg) * h + (split & (gsz - 1));
          const float* src = Ut + slot * 2048 + lane32;
          #pragma unroll
          for (int a = 0; a < 8; a++)
            #pragma unroll
            for (int b = 0; b < 8; b++)
              acc[a][b] += src[(a * 8 + b) * 32];
        }
        __syncthreads();
      }
      // group leaders write the full 32 x rpad segment tile (unique writer)
      if (active && (split & (gsz - 1)) == 0) {
        const int grow = s0 + (split << 4);
        const int gseg = grow >> lb;
        float* outp = (lb >= 10) ? (part + (l * 128 + chunk) * 2048)
                                 : (tl + gseg * 32 * rpad);
        float* base = outp + n0 * rpad + j0;
        #pragma unroll
        for (int a = 0; a < 8; a++) {
          *(float4*)&base[a * rpad]     = make_float4(acc[a][0], acc[a][1], acc[a][2], acc[a][3]);
          *(float4*)&base[a * rpad + 4] = make_float4(acc[a][4], acc[a][5], acc[a][6], acc[a][7]);
        }
      }
      #pragma unroll
      for (int a = 0; a < 8; a++)
        #pragma unroll
        for (int b = 0; b < 8; b++) acc[a][b] = 0.f;
    }
    __syncthreads();
  }
}

// ---------------- reduce: t[l][seg] = sum over chunks of part tiles (levels 0..6)
// grid: 254 blocks (one per segment), 256 threads, 8 floats each
__global__ __launch_bounds__(256)
void reduce_kernel(const float* __restrict__ part, float* __restrict__ t,
                   LevelParams P) {
  int b = blockIdx.x;
  int l = 0, segs = 2;
  while (b >= segs) { b -= segs; l++; segs <<= 1; }   // l in 0..6, b = seg index
  const int nch = 64 >> l;                            // chunks per segment
  const int tid = threadIdx.x;
  const float* src = part + (size_t)(l * 128 + b * nch) * 2048 + tid * 8;
  float s0 = 0.f, s1 = 0.f, s2 = 0.f, s3 = 0.f, s4 = 0.f, s5 = 0.f, s6 = 0.f, s7 = 0.f;
  for (int k = 0; k < nch; k++) {
    float4 v0 = *(const float4*)&src[k * 2048];
    float4 v1 = *(const float4*)&src[k * 2048 + 4];
    s0 += v0.x; s1 += v0.y; s2 += v0.z; s3 += v0.w;
    s4 += v1.x; s5 += v1.y; s6 += v1.z; s7 += v1.w;
  }
  float* dst = t + P.t_off[l] + b * 2048 + tid * 8;
  *(float4*)dst = make_float4(s0, s1, s2, s3);
  *(float4*)&dst[4] = make_float4(s4, s5, s6, s7);
}

// ---------------- y-pass level compute: U direct from global (wave-broadcast
// across the 8 ng lanes, L1-resident across column quads), t from XOR-swizzled
// LDS (conflict-free: bank quad = (c4 ^ ng) & 7, distinct per ng).
template<int RC>
__device__ __forceinline__ void level_mm(const float* __restrict__ ub,
                                         const float* __restrict__ tt,
                                         int ng, float acc[8][4]) {
  constexpr int RPL = (RC + 31) & ~31;   // LDS row stride (multiple of 32)
  #pragma unroll 4
  for (int c4 = 0; c4 < (RC >> 2); c4++) {
    const int tcol = ((c4 ^ ng) << 2);
    float4 tv0 = *(const float4*)&tt[0 * RPL + tcol];
    float4 tv1 = *(const float4*)&tt[1 * RPL + tcol];
    float4 tv2 = *(const float4*)&tt[2 * RPL + tcol];
    float4 tv3 = *(const float4*)&tt[3 * RPL + tcol];
    #pragma unroll
    for (int k = 0; k < 8; k++) {
      float4 uv = *(const float4*)&ub[k * RC + (c4 << 2)];
      acc[k][0] += uv.x * tv0.x + uv.y * tv0.y + uv.z * tv0.z + uv.w * tv0.w;
      acc[k][1] += uv.x * tv1.x + uv.y * tv1.y + uv.z * tv1.z + uv.w * tv1.w;
      acc[k][2] += uv.x * tv2.x + uv.y * tv2.y + uv.z * tv2.z + uv.w * tv2.w;
      acc[k][3] += uv.x * tv3.x + uv.y * tv3.y + uv.z * tv3.z + uv.w * tv3.w;
    }
  }
}

// ---------------- y-pass: out[n][i] = leaf(i) + s2 * sum_l sum_j U_l[i][j]*t_l[sib][n][j]
// grid: N/256 WGs, 256 threads; thread tile = 8 rows x 4 batches
// LDS 53760 B -> 3 blocks/CU (was 70656 B -> 2 blocks/CU)
__global__ __launch_bounds__(256, 3)
void ypass_kernel(const float* __restrict__ x,
                  const float* __restrict__ leaf,
                  const float* __restrict__ scale,
                  const float* __restrict__ t,
                  float* __restrict__ out,
                  LevelParams P) {
  __shared__ float smem[13440];  // 53760 B: phase A = 9216 (xT) + 4224 (Lb chunk)

  const int bid = blockIdx.x;
  const int tid = threadIdx.x;
  const int R0 = bid << 8;         // 256 rows per WG
  const int ig = tid >> 3;         // 0..31  -> i0l = ig*8
  const int ng = tid & 7;          // 0..7   -> n0 = ng*4
  const int i0l = ig << 3;
  const int n0 = ng << 2;

  const float sc = scale[0];
  const float s2 = sc * sc;

  float acc[8][4];
  #pragma unroll
  for (int k = 0; k < 8; k++)
    #pragma unroll
    for (int m = 0; m < 4; m++) acc[k][m] = 0.f;

  // ---- Phase A: leaf block-diagonal (leaf tile chunked 2x to halve LDS) ----
  {
    float* xT = smem;           // [256][36]
    float* Lb = smem + 9216;    // [4][32][33] = 4224 floats
    #pragma unroll 4
    for (int rep = 0; rep < 32; rep++) {
      xT[tid * 36 + rep] = x[rep * NN + R0 + tid];
    }
    const int bl = ig >> 2;           // 0..7: this thread's leaf block
    const int irow0 = (ig & 3) << 3;
    for (int ch = 0; ch < 2; ch++) {
      __syncthreads();   // xT staged (ch=0) / prev chunk compute done (ch=1)
      const float* lbase = leaf + ((R0 >> 5) + ch * 4) * 1024;
      for (int slot = tid; slot < 1024; slot += 256) {
        int flat = slot << 2;
        float4 v = *(const float4*)&lbase[flat];
        int b = flat >> 10;          // 0..3
        int tt_ = (flat >> 5) & 31;
        int s = flat & 31;
        float* dst = &Lb[b * 1056 + tt_ * 33 + s];
        dst[0] = v.x; dst[1] = v.y; dst[2] = v.z; dst[3] = v.w;
      }
      __syncthreads();
      if ((bl >> 2) == ch) {
        const int bll = bl & 3;
        #pragma unroll 4
        for (int s = 0; s < 32; s++) {
          float4 xv = *(const float4*)&xT[((bl << 5) + s) * 36 + n0];
          float xs[4] = {xv.x, xv.y, xv.z, xv.w};
          #pragma unroll
          for (int k = 0; k < 8; k++) {
            float L = Lb[bll * 1056 + (irow0 + k) * 33 + s];
            #pragma unroll
            for (int m = 0; m < 4; m++) acc[k][m] += L * xs[m];
          }
        }
      }
    }
    __syncthreads();
  }

  // ---- Phase B: levels. Sibling t staged to LDS swizzled; U read direct. ----
  float* ttl = smem;   // up to 8192 floats ([k][n][rpadL], col4 ^= (n>>2)&7)
  for (int l = 0; l < 12; l++) {
    const float* __restrict__ u = P.u[l];
    const int r = P.r[l], rpad = P.rpad[l], lb = P.lb[l];
    const int rpadL = (r + 31) & ~31;       // 64,64,...,64,64,32,32
    const float* tl = t + P.t_off[l];
    const int segf_g = rpad << 5;           // global segment floats
    const int segf_l = rpadL << 5;          // LDS segment floats
    const int span_sh = (lb >= 8) ? 0 : (8 - lb);
    const int bseg = R0 >> lb;
    const int total4 = (segf_g << span_sh) >> 2;
    for (int idx4 = tid; idx4 < total4; idx4 += 256) {
      int flat = idx4 << 2;
      int k, rem, n, c;
      if (rpad == 64)      { k = flat >> 11; rem = flat & 2047; n = rem >> 6; c = rem & 63; }
      else if (rpad == 32) { k = flat >> 10; rem = flat & 1023; n = rem >> 5; c = rem & 31; }
      else { k = flat / segf_g; rem = flat - k * segf_g; n = rem / rpad; c = rem - n * rpad; }
      int sib = (bseg + k) ^ 1;
      float4 v = *(const float4*)&tl[(size_t)sib * segf_g + rem];
      v.x *= s2; v.y *= s2; v.z *= s2; v.w *= s2;
      int c4s = (((c >> 2) ^ ((n >> 2) & 7)) << 2);
      *(float4*)&ttl[((k << 5) | n) * rpadL + c4s] = v;
    }
    __syncthreads();
    const int kseg = i0l >> lb;   // local staged segment of this thread's rows
    const float* tt = ttl + kseg * segf_l + n0 * rpadL;
    const float* ub = u + (size_t)(R0 + i0l) * r;
    if (r == 64)      level_mm<64>(ub, tt, ng, acc);
    else if (r == 52) level_mm<52>(ub, tt, ng, acc);
    else if (r == 32) level_mm<32>(ub, tt, ng, acc);
    else              level_mm<20>(ub, tt, ng, acc);
    __syncthreads();
  }

  // ---- epilogue: single write of y ----
  #pragma unroll
  for (int m = 0; m < 4; m++) {
    float4 o0 = make_float4(acc[0][m], acc[1][m], acc[2][m], acc[3][m]);
    float4 o1 = make_float4(acc[4][m], acc[5][m], acc[6][m], acc[7][m]);
    float* dst = out + (n0 + m) * NN + R0 + i0l;
    *(float4*)&dst[0] = o0;
    *(float4*)&dst[4] = o1;
  }
}

extern "C" void kernel_launch(void* const* d_in, const int* in_sizes, int n_in,
                              void* d_out, int out_size, void* d_ws, size_t ws_size,
                              hipStream_t stream) {
  const float* x     = (const float*)d_in[0];
  const float* leaf  = (const float*)d_in[1];
  const float* scale = (const float*)d_in[2];

  static const int RANKS[12] = {64,64,64,64,64,64,64,64,64,52,32,20};
  LevelParams P;
  int off = 0;
  for (int l = 0; l < 12; l++) {
    P.u[l] = (const float*)d_in[3 + l];
    P.r[l] = RANKS[l];
    P.rpad[l] = (RANKS[l] + 7) & ~7;
    P.lb[l] = 16 - l;
    P.t_off[l] = off;
    off += (2 << l) * 32 * P.rpad[l];
  }

  float* t = (float*)d_ws;
  float* part = t + off;                 // 7 levels * 128 chunks * 2048 floats

  tpass_kernel<<<dim3(12 * 128), dim3(256), 0, stream>>>(x, t, part, P);
  reduce_kernel<<<dim3(254), dim3(256), 0, stream>>>(part, t, P);
  ypass_kernel<<<dim3(NN / 256), dim3(256), 0, stream>>>(x, leaf, scale, t,
                                                         (float*)d_out, P);
}

// Round 4
// 611.750 us; speedup vs baseline: 1.2188x; 1.2188x over previous
//
#include <hip/hip_runtime.h>

#define NN 131072
#define BB 32

struct LevelParams {
  const float* u[12];
  int t_off[12];   // float offsets into workspace
  int r[12];
  int rpad[12];
  int lb[12];      // log2(bsz); bsz = 2^(16-level)
};

// ---------------- t-pass: t[seg][n][j] = sum_{s in seg} U[s][j] * x[n][s] --------
// grid: 12 levels * 128 chunks (1024 rows each), 256 threads. NO global atomics:
// cross-split combine via LDS tree; levels 0..6 write per-chunk partials
// (reduced by reduce_kernel), levels 7..11 write t directly (unique writer).
__global__ __launch_bounds__(256, 3)
void tpass_kernel(const float* __restrict__ x, float* __restrict__ t,
                  float* __restrict__ part, LevelParams P) {
  __shared__ float xT[128 * 36];   // [s][n], padded
  __shared__ float Ut[128 * 64];   // [s][rpad]; reused as 4x2048 reduction scratch

  const int bid = blockIdx.x;
  const int l = bid >> 7;
  const int chunk = bid & 127;
  const int tid = threadIdx.x;

  const float* __restrict__ u = P.u[l];
  const int r = P.r[l];
  const int rpad = P.rpad[l];
  const int lb = P.lb[l];
  float* __restrict__ tl = t + P.t_off[l];

  const int G = rpad >> 3;           // active j-groups
  const int split = tid >> 5;        // 0..7 : 16-row slice within 128-row window
  const int lane32 = tid & 31;
  const int n0 = (lane32 >> 3) << 3; // 0,8,16,24
  const int jg = lane32 & 7;
  const int j0 = jg << 3;
  const bool active = (jg < G);

  const int lg = (lb >= 7) ? 3 : (lb - 4);  // log2(splits per segment group)
  const int gsz = 1 << lg;

  float acc[8][8];
  #pragma unroll
  for (int a = 0; a < 8; a++)
    #pragma unroll
    for (int b = 0; b < 8; b++) acc[a][b] = 0.f;

  const int Rc = chunk << 10;
  const int r4 = rpad >> 2;
  const int uslots = 32 * rpad;      // (128*rpad)/4 float4 slots

  for (int sub = 0; sub < 8; sub++) {
    const int s0 = Rc + (sub << 7);
    // stage x transposed: xT[ss][n]
    #pragma unroll
    for (int rep = 0; rep < 16; rep++) {
      int idx = rep * 256 + tid;
      int ss = idx & 127;
      int n = idx >> 7;
      xT[ss * 36 + n] = x[n * NN + s0 + ss];
    }
    // stage U rows (zero-pad j>=r)
    for (int slot = tid; slot < uslots; slot += 256) {
      int row = slot / r4;
      int c4 = slot - row * r4;
      int j = c4 << 2;
      float4 v;
      if (j < r) v = *(const float4*)&u[(s0 + row) * r + j];
      else       v = make_float4(0.f, 0.f, 0.f, 0.f);
      *(float4*)&Ut[row * rpad + j] = v;
    }
    __syncthreads();

    if (active) {
      const int sl0 = split << 4;
      #pragma unroll 4
      for (int ss = 0; ss < 16; ss++) {
        const int sl = sl0 + ss;
        float4 xa = *(const float4*)&xT[sl * 36 + n0];
        float4 xb = *(const float4*)&xT[sl * 36 + n0 + 4];
        float4 ua = *(const float4*)&Ut[sl * rpad + j0];
        float4 ub = *(const float4*)&Ut[sl * rpad + j0 + 4];
        float xs[8] = {xa.x, xa.y, xa.z, xa.w, xb.x, xb.y, xb.z, xb.w};
        float us[8] = {ua.x, ua.y, ua.z, ua.w, ub.x, ub.y, ub.z, ub.w};
        #pragma unroll
        for (int a = 0; a < 8; a++)
          #pragma unroll
          for (int b = 0; b < 8; b++)
            acc[a][b] += xs[a] * us[b];
      }
    }

    // block-uniform flush: end of chunk, or the 128-row window ends a segment
    const bool fl = (sub == 7) || (((s0 + 128) >> lb) != (s0 >> lb));
    if (fl) {
      __syncthreads();   // all compute reads of Ut done before reusing as scratch
      // tree-reduce across the gsz splits that share each segment
      for (int h = gsz >> 1; h >= 1; h >>= 1) {
        const int sig = split & (gsz - 1);
        if (active && sig >= h && sig < (h << 1)) {
          int rid = split - h;                         // reader split id
          int slot = (rid >> lg) * h + (rid & (gsz - 1));  // 0..3
          float* dst = Ut + slot * 2048 + lane32;      // [(a*8+b)][lane32]
          #pragma unroll
          for (int a = 0; a < 8; a++)
            #pragma unroll
            for (int b = 0; b < 8; b++)
              dst[(a * 8 + b) * 32] = acc[a][b];
        }
        __syncthreads();
        if (active && (split & (gsz - 1)) < h) {
          int slot = (split >> lg) * h + (split & (gsz - 1));
          const float* src = Ut + slot * 2048 + lane32;
          #pragma unroll
          for (int a = 0; a < 8; a++)
            #pragma unroll
            for (int b = 0; b < 8; b++)
              acc[a][b] += src[(a * 8 + b) * 32];
        }
        __syncthreads();
      }
      // group leaders write the full 32 x rpad segment tile (unique writer)
      if (active && (split & (gsz - 1)) == 0) {
        const int grow = s0 + (split << 4);
        const int gseg = grow >> lb;
        float* outp = (lb >= 10) ? (part + (l * 128 + chunk) * 2048)
                                 : (tl + gseg * 32 * rpad);
        float* base = outp + n0 * rpad + j0;
        #pragma unroll
        for (int a = 0; a < 8; a++) {
          *(float4*)&base[a * rpad]     = make_float4(acc[a][0], acc[a][1], acc[a][2], acc[a][3]);
          *(float4*)&base[a * rpad + 4] = make_float4(acc[a][4], acc[a][5], acc[a][6], acc[a][7]);
        }
      }
      #pragma unroll
      for (int a = 0; a < 8; a++)
        #pragma unroll
        for (int b = 0; b < 8; b++) acc[a][b] = 0.f;
    }
    __syncthreads();
  }
}

// ---------------- reduce: t[l][seg] = sum over chunks of part tiles (levels 0..6)
// grid: 254 blocks (one per segment), 256 threads, 8 floats each
__global__ __launch_bounds__(256)
void reduce_kernel(const float* __restrict__ part, float* __restrict__ t,
                   LevelParams P) {
  int b = blockIdx.x;
  int l = 0, segs = 2;
  while (b >= segs) { b -= segs; l++; segs <<= 1; }   // l in 0..6, b = seg index
  const int nch = 64 >> l;                            // chunks per segment
  const int tid = threadIdx.x;
  const float* src = part + (size_t)(l * 128 + b * nch) * 2048 + tid * 8;
  float s0 = 0.f, s1 = 0.f, s2 = 0.f, s3 = 0.f, s4 = 0.f, s5 = 0.f, s6 = 0.f, s7 = 0.f;
  for (int k = 0; k < nch; k++) {
    float4 v0 = *(const float4*)&src[k * 2048];
    float4 v1 = *(const float4*)&src[k * 2048 + 4];
    s0 += v0.x; s1 += v0.y; s2 += v0.z; s3 += v0.w;
    s4 += v1.x; s5 += v1.y; s6 += v1.z; s7 += v1.w;
  }
  float* dst = t + P.t_off[l] + b * 2048 + tid * 8;
  *(float4*)dst = make_float4(s0, s1, s2, s3);
  *(float4*)&dst[4] = make_float4(s4, s5, s6, s7);
}

// ---------------- y-pass: out[n][i] = leaf(i) + s2 * sum_l sum_j U_l[i][j]*t_l[sib][n][j]
// grid: N/256 WGs, 256 threads; thread tile = 8 rows x 4 batches.
// Baseline structure (LDS-staged Uc, no spill) + XOR-swizzled LDS layouts:
//   ttl: quad col ^= ng  (row stride rpadL multiple of 32)  -> t reads conflict-free
//   Uc : quad idx ^= (row>>3)&7 -> U reads broadcast across ng, distinct bank
//        group per ig lane-group (read swizzle MUST be ig&7 to match write side)
__global__ __launch_bounds__(256, 2)
void ypass_kernel(const float* __restrict__ x,
                  const float* __restrict__ leaf,
                  const float* __restrict__ scale,
                  const float* __restrict__ t,
                  float* __restrict__ out,
                  LevelParams P) {
  __shared__ float smem[13440];  // 53760 B: phase A = 9216 (xT) + 4224 (Lb chunk)
                                 //          phase B = 8192 (ttl) + 2048 (Uc)

  const int bid = blockIdx.x;
  const int tid = threadIdx.x;
  const int R0 = bid << 8;         // 256 rows per WG
  const int ig = tid >> 3;         // 0..31  -> i0l = ig*8
  const int ng = tid & 7;          // 0..7   -> n0 = ng*4
  const int i0l = ig << 3;
  const int n0 = ng << 2;

  const float sc = scale[0];
  const float s2 = sc * sc;

  float acc[8][4];
  #pragma unroll
  for (int k = 0; k < 8; k++)
    #pragma unroll
    for (int m = 0; m < 4; m++) acc[k][m] = 0.f;

  // ---- Phase A: leaf block-diagonal (leaf tile chunked 2x to halve LDS) ----
  {
    float* xT = smem;           // [256][36]
    float* Lb = smem + 9216;    // [4][32][33] = 4224 floats
    #pragma unroll 4
    for (int rep = 0; rep < 32; rep++) {
      xT[tid * 36 + rep] = x[rep * NN + R0 + tid];
    }
    const int bl = ig >> 2;           // 0..7: this thread's leaf block
    const int irow0 = (ig & 3) << 3;
    for (int ch = 0; ch < 2; ch++) {
      __syncthreads();   // xT staged (ch=0) / prev chunk compute done (ch=1)
      const float* lbase = leaf + ((R0 >> 5) + ch * 4) * 1024;
      for (int slot = tid; slot < 1024; slot += 256) {
        int flat = slot << 2;
        float4 v = *(const float4*)&lbase[flat];
        int b = flat >> 10;          // 0..3
        int tt_ = (flat >> 5) & 31;
        int s = flat & 31;
        float* dst = &Lb[b * 1056 + tt_ * 33 + s];
        dst[0] = v.x; dst[1] = v.y; dst[2] = v.z; dst[3] = v.w;
      }
      __syncthreads();
      if ((bl >> 2) == ch) {
        const int bll = bl & 3;
        #pragma unroll 4
        for (int s = 0; s < 32; s++) {
          float4 xv = *(const float4*)&xT[((bl << 5) + s) * 36 + n0];
          float xs[4] = {xv.x, xv.y, xv.z, xv.w};
          #pragma unroll
          for (int k = 0; k < 8; k++) {
            float L = Lb[bll * 1056 + (irow0 + k) * 33 + s];
            #pragma unroll
            for (int m = 0; m < 4; m++) acc[k][m] += L * xs[m];
          }
        }
      }
    }
    __syncthreads();
  }

  // ---- Phase B: levels. Sibling t staged swizzled; Uc staged swizzled. ----
  float* ttl = smem;          // up to 8192 floats: [k][n][rpadL], quad ^= n>>2
  float* Uc  = smem + 8192;   // 2048 floats: 512 quads, quad idx ^= (slot>>4)&7
  for (int l = 0; l < 12; l++) {
    const float* __restrict__ u = P.u[l];
    const int r = P.r[l], rpad = P.rpad[l], lb = P.lb[l];
    const int rpadL = (r + 31) & ~31;       // 64 (r>=52), 32 (r<=32)
    const float* tl = t + P.t_off[l];
    const int segf_g = rpad << 5;           // global segment floats
    const int segf_l = rpadL << 5;          // LDS segment floats
    const int span_sh = (lb >= 8) ? 0 : (8 - lb);
    const int bseg = R0 >> lb;
    const int total4 = (segf_g << span_sh) >> 2;
    for (int idx4 = tid; idx4 < total4; idx4 += 256) {
      int flat = idx4 << 2;
      int k, rem, n, c;
      if (rpad == 64)      { k = flat >> 11; rem = flat & 2047; n = rem >> 6; c = rem & 63; }
      else if (rpad == 32) { k = flat >> 10; rem = flat & 1023; n = rem >> 5; c = rem & 31; }
      else { k = flat / segf_g; rem = flat - k * segf_g; n = rem / rpad; c = rem - n * rpad; }
      int sib = (bseg + k) ^ 1;
      float4 v = *(const float4*)&tl[(size_t)sib * segf_g + rem];
      v.x *= s2; v.y *= s2; v.z *= s2; v.w *= s2;
      int c4s = (((c >> 2) ^ (n >> 2)) << 2);
      *(float4*)&ttl[((k << 5) | n) * rpadL + c4s] = v;
    }
    __syncthreads();
    const int kseg = i0l >> lb;   // local staged segment of this thread's rows
    const float* tt = ttl + kseg * segf_l + n0 * rpadL;
    const int nj = rpad >> 3;
    for (int jc = 0; jc < nj; jc++) {
      // stage Uc (zero-pad j>=r), swizzled: quad = slot ^ ((slot>>4)&7)
      #pragma unroll
      for (int rep = 0; rep < 2; rep++) {
        int slot = rep * 256 + tid;
        int row = slot >> 1;
        int h = (slot & 1) << 2;
        int j = (jc << 3) + h;
        float4 v;
        if (j < r) v = *(const float4*)&u[(R0 + row) * r + j];
        else       v = make_float4(0.f, 0.f, 0.f, 0.f);
        int q = slot ^ ((slot >> 4) & 7);
        *(float4*)&Uc[q << 2] = v;
      }
      __syncthreads();
      #pragma unroll
      for (int half = 0; half < 2; half++) {
        const int jq = (jc << 1) | half;
        const int tcol = (jq ^ ng) << 2;
        float4 tv0 = *(const float4*)&tt[0 * rpadL + tcol];
        float4 tv1 = *(const float4*)&tt[1 * rpadL + tcol];
        float4 tv2 = *(const float4*)&tt[2 * rpadL + tcol];
        float4 tv3 = *(const float4*)&tt[3 * rpadL + tcol];
        #pragma unroll
        for (int k = 0; k < 8; k++) {
          int q = ((((i0l + k) << 1) | half) ^ (ig & 7));
          float4 uv = *(const float4*)&Uc[q << 2];
          acc[k][0] += uv.x * tv0.x + uv.y * tv0.y + uv.z * tv0.z + uv.w * tv0.w;
          acc[k][1] += uv.x * tv1.x + uv.y * tv1.y + uv.z * tv1.z + uv.w * tv1.w;
          acc[k][2] += uv.x * tv2.x + uv.y * tv2.y + uv.z * tv2.z + uv.w * tv2.w;
          acc[k][3] += uv.x * tv3.x + uv.y * tv3.y + uv.z * tv3.z + uv.w * tv3.w;
        }
      }
      __syncthreads();
    }
  }

  // ---- epilogue: single write of y ----
  #pragma unroll
  for (int m = 0; m < 4; m++) {
    float4 o0 = make_float4(acc[0][m], acc[1][m], acc[2][m], acc[3][m]);
    float4 o1 = make_float4(acc[4][m], acc[5][m], acc[6][m], acc[7][m]);
    float* dst = out + (n0 + m) * NN + R0 + i0l;
    *(float4*)&dst[0] = o0;
    *(float4*)&dst[4] = o1;
  }
}

extern "C" void kernel_launch(void* const* d_in, const int* in_sizes, int n_in,
                              void* d_out, int out_size, void* d_ws, size_t ws_size,
                              hipStream_t stream) {
  const float* x     = (const float*)d_in[0];
  const float* leaf  = (const float*)d_in[1];
  const float* scale = (const float*)d_in[2];

  static const int RANKS[12] = {64,64,64,64,64,64,64,64,64,52,32,20};
  LevelParams P;
  int off = 0;
  for (int l = 0; l < 12; l++) {
    P.u[l] = (const float*)d_in[3 + l];
    P.r[l] = RANKS[l];
    P.rpad[l] = (RANKS[l] + 7) & ~7;
    P.lb[l] = 16 - l;
    P.t_off[l] = off;
    off += (2 << l) * 32 * P.rpad[l];
  }

  float* t = (float*)d_ws;
  float* part = t + off;                 // 7 levels * 128 chunks * 2048 floats

  tpass_kernel<<<dim3(12 * 128), dim3(256), 0, stream>>>(x, t, part, P);
  reduce_kernel<<<dim3(254), dim3(256), 0, stream>>>(part, t, P);
  ypass_kernel<<<dim3(NN / 256), dim3(256), 0, stream>>>(x, leaf, scale, t,
                                                         (float*)d_out, P);
}

// Round 5
// 608.202 us; speedup vs baseline: 1.2259x; 1.0058x over previous
//
#include <hip/hip_runtime.h>

#define NN 131072
#define BB 32

struct LevelParams {
  const float* u[12];
  int t_off[12];   // float offsets into workspace
  int r[12];
  int rpad[12];
  int lb[12];      // log2(bsz); bsz = 2^(16-level)
};

// ---------------- t-pass: t[seg][n][j] = sum_{s in seg} U[s][j] * x[n][s] --------
// grid: 12 levels * 128 chunks (1024 rows each), 256 threads. NO global atomics:
// cross-split combine via LDS tree; levels 0..6 write per-chunk partials
// (reduced by reduce_kernel), levels 7..11 write t directly (unique writer).
// LDS conflict fixes: xT staged via float4 writes (conflict-free b128 slots);
// Ut quad-XOR-swizzled: Q = (c4&8) | ((c4&7)^(c4>>3)^(row&7)), row stride 32/64.
__global__ __launch_bounds__(256, 3)
void tpass_kernel(const float* __restrict__ x, float* __restrict__ t,
                  float* __restrict__ part, LevelParams P) {
  __shared__ float xT[128 * 36];   // [s][n], padded
  __shared__ float Ut[128 * 64];   // [s][rpadS] swizzled; reused as 4x2048 scratch

  const int bid = blockIdx.x;
  const int l = bid >> 7;
  const int chunk = bid & 127;
  const int tid = threadIdx.x;

  const float* __restrict__ u = P.u[l];
  const int r = P.r[l];
  const int rpad = P.rpad[l];
  const int lb = P.lb[l];
  float* __restrict__ tl = t + P.t_off[l];

  const int G = rpad >> 3;           // active j-groups
  const int split = tid >> 5;        // 0..7 : 16-row slice within 128-row window
  const int lane32 = tid & 31;
  const int n0 = (lane32 >> 3) << 3; // 0,8,16,24
  const int jg = lane32 & 7;
  const int j0 = jg << 3;
  const bool active = (jg < G);

  const int lg = (lb >= 7) ? 3 : (lb - 4);  // log2(splits per segment group)
  const int gsz = 1 << lg;

  const int rpadS = (rpad <= 32) ? 32 : 64;  // swizzled LDS row stride
  // precomputed read-swizzle pieces for quads qa=2*jg, qb=2*jg+1
  const int qa = jg << 1, qb = qa | 1;
  const int qa_hi = qa & 8, qa_lo = (qa & 7) ^ (qa >> 3);
  const int qb_hi = qb & 8, qb_lo = (qb & 7) ^ (qb >> 3);

  float acc[8][8];
  #pragma unroll
  for (int a = 0; a < 8; a++)
    #pragma unroll
    for (int b = 0; b < 8; b++) acc[a][b] = 0.f;

  const int Rc = chunk << 10;
  const int r4 = rpad >> 2;
  const int uslots = 32 * rpad;      // (128*rpad)/4 float4 slots

  const int ss_st = tid & 127;       // xT staging: this thread's column
  const int hi_st = (tid >> 7) << 4; // n-base 0 or 16

  for (int sub = 0; sub < 8; sub++) {
    const int s0 = Rc + (sub << 7);
    // stage x transposed: xT[ss][n], float4 n-chunks (conflict-free b128 writes)
    #pragma unroll
    for (int rep4 = 0; rep4 < 4; rep4++) {
      const int nb = hi_st + (rep4 << 2);
      float4 v;
      v.x = x[(nb + 0) * NN + s0 + ss_st];
      v.y = x[(nb + 1) * NN + s0 + ss_st];
      v.z = x[(nb + 2) * NN + s0 + ss_st];
      v.w = x[(nb + 3) * NN + s0 + ss_st];
      *(float4*)&xT[ss_st * 36 + nb] = v;
    }
    // stage U rows swizzled (zero-pad j>=r)
    for (int slot = tid; slot < uslots; slot += 256) {
      int row = slot / r4;
      int c4 = slot - row * r4;
      int j = c4 << 2;
      float4 v;
      if (j < r) v = *(const float4*)&u[(s0 + row) * r + j];
      else       v = make_float4(0.f, 0.f, 0.f, 0.f);
      int Q = (c4 & 8) | (((c4 & 7) ^ (c4 >> 3) ^ (row & 7)));
      *(float4*)&Ut[row * rpadS + (Q << 2)] = v;
    }
    __syncthreads();

    if (active) {
      const int sl0 = split << 4;
      #pragma unroll 4
      for (int ss = 0; ss < 16; ss++) {
        const int sl = sl0 + ss;
        const int sx = sl & 7;
        float4 xa = *(const float4*)&xT[sl * 36 + n0];
        float4 xb = *(const float4*)&xT[sl * 36 + n0 + 4];
        float4 ua = *(const float4*)&Ut[sl * rpadS + ((qa_hi | (qa_lo ^ sx)) << 2)];
        float4 ub = *(const float4*)&Ut[sl * rpadS + ((qb_hi | (qb_lo ^ sx)) << 2)];
        float xs[8] = {xa.x, xa.y, xa.z, xa.w, xb.x, xb.y, xb.z, xb.w};
        float us[8] = {ua.x, ua.y, ua.z, ua.w, ub.x, ub.y, ub.z, ub.w};
        #pragma unroll
        for (int a = 0; a < 8; a++)
          #pragma unroll
          for (int b = 0; b < 8; b++)
            acc[a][b] += xs[a] * us[b];
      }
    }

    // block-uniform flush: end of chunk, or the 128-row window ends a segment
    const bool fl = (sub == 7) || (((s0 + 128) >> lb) != (s0 >> lb));
    if (fl) {
      __syncthreads();   // all compute reads of Ut done before reusing as scratch
      // tree-reduce across the gsz splits that share each segment
      for (int h = gsz >> 1; h >= 1; h >>= 1) {
        const int sig = split & (gsz - 1);
        if (active && sig >= h && sig < (h << 1)) {
          int rid = split - h;                         // reader split id
          int slot = (rid >> lg) * h + (rid & (gsz - 1));  // 0..3
          float* dst = Ut + slot * 2048 + lane32;      // [(a*8+b)][lane32]
          #pragma unroll
          for (int a = 0; a < 8; a++)
            #pragma unroll
            for (int b = 0; b < 8; b++)
              dst[(a * 8 + b) * 32] = acc[a][b];
        }
        __syncthreads();
        if (active && (split & (gsz - 1)) < h) {
          int slot = (split >> lg) * h + (split & (gsz - 1));
          const float* src = Ut + slot * 2048 + lane32;
          #pragma unroll
          for (int a = 0; a < 8; a++)
            #pragma unroll
            for (int b = 0; b < 8; b++)
              acc[a][b] += src[(a * 8 + b) * 32];
        }
        __syncthreads();
      }
      // group leaders write the full 32 x rpad segment tile (unique writer)
      if (active && (split & (gsz - 1)) == 0) {
        const int grow = s0 + (split << 4);
        const int gseg = grow >> lb;
        float* outp = (lb >= 10) ? (part + (l * 128 + chunk) * 2048)
                                 : (tl + gseg * 32 * rpad);
        float* base = outp + n0 * rpad + j0;
        #pragma unroll
        for (int a = 0; a < 8; a++) {
          *(float4*)&base[a * rpad]     = make_float4(acc[a][0], acc[a][1], acc[a][2], acc[a][3]);
          *(float4*)&base[a * rpad + 4] = make_float4(acc[a][4], acc[a][5], acc[a][6], acc[a][7]);
        }
      }
      #pragma unroll
      for (int a = 0; a < 8; a++)
        #pragma unroll
        for (int b = 0; b < 8; b++) acc[a][b] = 0.f;
    }
    __syncthreads();
  }
}

// ---------------- reduce: t[l][seg] = sum over chunks of part tiles (levels 0..6)
// grid: 254 blocks (one per segment), 256 threads, 8 floats each
__global__ __launch_bounds__(256)
void reduce_kernel(const float* __restrict__ part, float* __restrict__ t,
                   LevelParams P) {
  int b = blockIdx.x;
  int l = 0, segs = 2;
  while (b >= segs) { b -= segs; l++; segs <<= 1; }   // l in 0..6, b = seg index
  const int nch = 64 >> l;                            // chunks per segment
  const int tid = threadIdx.x;
  const float* src = part + (size_t)(l * 128 + b * nch) * 2048 + tid * 8;
  float s0 = 0.f, s1 = 0.f, s2 = 0.f, s3 = 0.f, s4 = 0.f, s5 = 0.f, s6 = 0.f, s7 = 0.f;
  for (int k = 0; k < nch; k++) {
    float4 v0 = *(const float4*)&src[k * 2048];
    float4 v1 = *(const float4*)&src[k * 2048 + 4];
    s0 += v0.x; s1 += v0.y; s2 += v0.z; s3 += v0.w;
    s4 += v1.x; s5 += v1.y; s6 += v1.z; s7 += v1.w;
  }
  float* dst = t + P.t_off[l] + b * 2048 + tid * 8;
  *(float4*)dst = make_float4(s0, s1, s2, s3);
  *(float4*)&dst[4] = make_float4(s4, s5, s6, s7);
}

// ---------------- y-pass: out[n][i] = leaf(i) + s2 * sum_l sum_j U_l[i][j]*t_l[sib][n][j]
// grid: N/256 WGs, 256 threads; thread tile = 8 rows x 4 batches.
// Baseline structure (LDS-staged Uc, no spill) + XOR-swizzled LDS layouts:
//   ttl: quad col ^= ng  (row stride rpadL multiple of 32)  -> t reads conflict-free
//   Uc : quad idx ^= (row>>3)&7 -> U reads broadcast across ng, distinct bank
//        group per ig lane-group (read swizzle MUST be ig&7 to match write side)
__global__ __launch_bounds__(256, 2)
void ypass_kernel(const float* __restrict__ x,
                  const float* __restrict__ leaf,
                  const float* __restrict__ scale,
                  const float* __restrict__ t,
                  float* __restrict__ out,
                  LevelParams P) {
  __shared__ float smem[13440];  // 53760 B: phase A = 9216 (xT) + 4224 (Lb chunk)
                                 //          phase B = 8192 (ttl) + 2048 (Uc)

  const int bid = blockIdx.x;
  const int tid = threadIdx.x;
  const int R0 = bid << 8;         // 256 rows per WG
  const int ig = tid >> 3;         // 0..31  -> i0l = ig*8
  const int ng = tid & 7;          // 0..7   -> n0 = ng*4
  const int i0l = ig << 3;
  const int n0 = ng << 2;

  const float sc = scale[0];
  const float s2 = sc * sc;

  float acc[8][4];
  #pragma unroll
  for (int k = 0; k < 8; k++)
    #pragma unroll
    for (int m = 0; m < 4; m++) acc[k][m] = 0.f;

  // ---- Phase A: leaf block-diagonal (leaf tile chunked 2x to halve LDS) ----
  {
    float* xT = smem;           // [256][36]
    float* Lb = smem + 9216;    // [4][32][33] = 4224 floats
    #pragma unroll 4
    for (int rep = 0; rep < 32; rep++) {
      xT[tid * 36 + rep] = x[rep * NN + R0 + tid];
    }
    const int bl = ig >> 2;           // 0..7: this thread's leaf block
    const int irow0 = (ig & 3) << 3;
    for (int ch = 0; ch < 2; ch++) {
      __syncthreads();   // xT staged (ch=0) / prev chunk compute done (ch=1)
      const float* lbase = leaf + ((R0 >> 5) + ch * 4) * 1024;
      for (int slot = tid; slot < 1024; slot += 256) {
        int flat = slot << 2;
        float4 v = *(const float4*)&lbase[flat];
        int b = flat >> 10;          // 0..3
        int tt_ = (flat >> 5) & 31;
        int s = flat & 31;
        float* dst = &Lb[b * 1056 + tt_ * 33 + s];
        dst[0] = v.x; dst[1] = v.y; dst[2] = v.z; dst[3] = v.w;
      }
      __syncthreads();
      if ((bl >> 2) == ch) {
        const int bll = bl & 3;
        #pragma unroll 4
        for (int s = 0; s < 32; s++) {
          float4 xv = *(const float4*)&xT[((bl << 5) + s) * 36 + n0];
          float xs[4] = {xv.x, xv.y, xv.z, xv.w};
          #pragma unroll
          for (int k = 0; k < 8; k++) {
            float L = Lb[bll * 1056 + (irow0 + k) * 33 + s];
            #pragma unroll
            for (int m = 0; m < 4; m++) acc[k][m] += L * xs[m];
          }
        }
      }
    }
    __syncthreads();
  }

  // ---- Phase B: levels. Sibling t staged swizzled; Uc staged swizzled. ----
  float* ttl = smem;          // up to 8192 floats: [k][n][rpadL], quad ^= n>>2
  float* Uc  = smem + 8192;   // 2048 floats: 512 quads, quad idx ^= (slot>>4)&7
  for (int l = 0; l < 12; l++) {
    const float* __restrict__ u = P.u[l];
    const int r = P.r[l], rpad = P.rpad[l], lb = P.lb[l];
    const int rpadL = (r + 31) & ~31;       // 64 (r>=52), 32 (r<=32)
    const float* tl = t + P.t_off[l];
    const int segf_g = rpad << 5;           // global segment floats
    const int segf_l = rpadL << 5;          // LDS segment floats
    const int span_sh = (lb >= 8) ? 0 : (8 - lb);
    const int bseg = R0 >> lb;
    const int total4 = (segf_g << span_sh) >> 2;
    for (int idx4 = tid; idx4 < total4; idx4 += 256) {
      int flat = idx4 << 2;
      int k, rem, n, c;
      if (rpad == 64)      { k = flat >> 11; rem = flat & 2047; n = rem >> 6; c = rem & 63; }
      else if (rpad == 32) { k = flat >> 10; rem = flat & 1023; n = rem >> 5; c = rem & 31; }
      else { k = flat / segf_g; rem = flat - k * segf_g; n = rem / rpad; c = rem - n * rpad; }
      int sib = (bseg + k) ^ 1;
      float4 v = *(const float4*)&tl[(size_t)sib * segf_g + rem];
      v.x *= s2; v.y *= s2; v.z *= s2; v.w *= s2;
      int c4s = (((c >> 2) ^ (n >> 2)) << 2);
      *(float4*)&ttl[((k << 5) | n) * rpadL + c4s] = v;
    }
    __syncthreads();
    const int kseg = i0l >> lb;   // local staged segment of this thread's rows
    const float* tt = ttl + kseg * segf_l + n0 * rpadL;
    const int nj = rpad >> 3;
    for (int jc = 0; jc < nj; jc++) {
      // stage Uc (zero-pad j>=r), swizzled: quad = slot ^ ((slot>>4)&7)
      #pragma unroll
      for (int rep = 0; rep < 2; rep++) {
        int slot = rep * 256 + tid;
        int row = slot >> 1;
        int h = (slot & 1) << 2;
        int j = (jc << 3) + h;
        float4 v;
        if (j < r) v = *(const float4*)&u[(R0 + row) * r + j];
        else       v = make_float4(0.f, 0.f, 0.f, 0.f);
        int q = slot ^ ((slot >> 4) & 7);
        *(float4*)&Uc[q << 2] = v;
      }
      __syncthreads();
      #pragma unroll
      for (int half = 0; half < 2; half++) {
        const int jq = (jc << 1) | half;
        const int tcol = (jq ^ ng) << 2;
        float4 tv0 = *(const float4*)&tt[0 * rpadL + tcol];
        float4 tv1 = *(const float4*)&tt[1 * rpadL + tcol];
        float4 tv2 = *(const float4*)&tt[2 * rpadL + tcol];
        float4 tv3 = *(const float4*)&tt[3 * rpadL + tcol];
        #pragma unroll
        for (int k = 0; k < 8; k++) {
          int q = ((((i0l + k) << 1) | half) ^ (ig & 7));
          float4 uv = *(const float4*)&Uc[q << 2];
          acc[k][0] += uv.x * tv0.x + uv.y * tv0.y + uv.z * tv0.z + uv.w * tv0.w;
          acc[k][1] += uv.x * tv1.x + uv.y * tv1.y + uv.z * tv1.z + uv.w * tv1.w;
          acc[k][2] += uv.x * tv2.x + uv.y * tv2.y + uv.z * tv2.z + uv.w * tv2.w;
          acc[k][3] += uv.x * tv3.x + uv.y * tv3.y + uv.z * tv3.z + uv.w * tv3.w;
        }
      }
      __syncthreads();
    }
  }

  // ---- epilogue: single write of y ----
  #pragma unroll
  for (int m = 0; m < 4; m++) {
    float4 o0 = make_float4(acc[0][m], acc[1][m], acc[2][m], acc[3][m]);
    float4 o1 = make_float4(acc[4][m], acc[5][m], acc[6][m], acc[7][m]);
    float* dst = out + (n0 + m) * NN + R0 + i0l;
    *(float4*)&dst[0] = o0;
    *(float4*)&dst[4] = o1;
  }
}

extern "C" void kernel_launch(void* const* d_in, const int* in_sizes, int n_in,
                              void* d_out, int out_size, void* d_ws, size_t ws_size,
                              hipStream_t stream) {
  const float* x     = (const float*)d_in[0];
  const float* leaf  = (const float*)d_in[1];
  const float* scale = (const float*)d_in[2];

  static const int RANKS[12] = {64,64,64,64,64,64,64,64,64,52,32,20};
  LevelParams P;
  int off = 0;
  for (int l = 0; l < 12; l++) {
    P.u[l] = (const float*)d_in[3 + l];
    P.r[l] = RANKS[l];
    P.rpad[l] = (RANKS[l] + 7) & ~7;
    P.lb[l] = 16 - l;
    P.t_off[l] = off;
    off += (2 << l) * 32 * P.rpad[l];
  }

  float* t = (float*)d_ws;
  float* part = t + off;                 // 7 levels * 128 chunks * 2048 floats

  tpass_kernel<<<dim3(12 * 128), dim3(256), 0, stream>>>(x, t, part, P);
  reduce_kernel<<<dim3(254), dim3(256), 0, stream>>>(part, t, P);
  ypass_kernel<<<dim3(NN / 256), dim3(256), 0, stream>>>(x, leaf, scale, t,
                                                         (float*)d_out, P);
}

// Round 8
// 579.154 us; speedup vs baseline: 1.2874x; 1.0502x over previous
//
#include <hip/hip_runtime.h>

#define NN 131072
#define BB 32

struct LevelParams {
  const float* u[12];
  int t_off[12];   // float offsets into workspace
  int r[12];
  int rpad[12];
  int lb[12];      // log2(bsz); bsz = 2^(16-level)
};

// ---------------- t-pass: t[seg][n][j] = sum_{s in seg} U[s][j] * x[n][s] --------
// grid: 12 levels * 128 chunks (1024 rows each), 256 threads.
// U stream (HBM-miss, ~900cy) register-prefetched one sub ahead (T14): loads for
// sub k+1 issue right after sub k's top barrier and complete under sub k's FMAs.
// Staging address math (slot/r4 divides, XOR-swizzle quads) hoisted out of the loop.
__global__ __launch_bounds__(256, 3)
void tpass_kernel(const float* __restrict__ x, float* __restrict__ t,
                  float* __restrict__ part, LevelParams P) {
  __shared__ float xT[128 * 36];   // [s][n], padded
  __shared__ float Ut[128 * 64];   // [s][rpadS] swizzled; reused as 4x2048 scratch

  const int bid = blockIdx.x;
  const int l = bid >> 7;
  const int chunk = bid & 127;
  const int tid = threadIdx.x;

  const float* __restrict__ u = P.u[l];
  const int r = P.r[l];
  const int rpad = P.rpad[l];
  const int lb = P.lb[l];
  float* __restrict__ tl = t + P.t_off[l];

  const int G = rpad >> 3;           // active j-groups
  const int split = tid >> 5;        // 0..7 : 16-row slice within 128-row window
  const int lane32 = tid & 31;
  const int n0 = (lane32 >> 3) << 3; // 0,8,16,24
  const int jg = lane32 & 7;
  const int j0 = jg << 3;
  const bool active = (jg < G);

  const int lg = (lb >= 7) ? 3 : (lb - 4);  // log2(splits per segment group)
  const int gsz = 1 << lg;

  const int rpadS = (rpad <= 32) ? 32 : 64;  // swizzled LDS row stride
  // read-swizzle pieces for quads qa=2*jg, qb=2*jg+1
  const int qa = jg << 1, qb = qa | 1;
  const int qa_hi = qa & 8, qa_lo = (qa & 7) ^ (qa >> 3);
  const int qb_hi = qb & 8, qb_lo = (qb & 7) ^ (qb >> 3);

  const int Rc = chunk << 10;
  const int r4 = rpad >> 2;
  const int uslots = 32 * rpad;      // (128*rpad)/4 float4 slots

  // ---- sub-invariant U staging descriptors (divides done once) ----
  int uoff[8];   // row*r + j  (>=0: load), -1: zero-pad write, -2: no slot
  int ldso[8];   // swizzled LDS float offset
  #pragma unroll
  for (int i = 0; i < 8; i++) {
    int slot = tid + (i << 8);
    if (slot < uslots) {
      int row = slot / r4;
      int c4 = slot - row * r4;
      int j = c4 << 2;
      int Q = (c4 & 8) | ((c4 & 7) ^ (c4 >> 3) ^ (row & 7));
      ldso[i] = row * rpadS + (Q << 2);
      uoff[i] = (j < r) ? (row * r + j) : -1;
    } else {
      uoff[i] = -2;
      ldso[i] = 0;
    }
  }

  const int ss_st = tid & 127;       // xT staging: this thread's column
  const int hi_st = (tid >> 7) << 4; // n-base 0 or 16

  float acc[8][8];
  #pragma unroll
  for (int a = 0; a < 8; a++)
    #pragma unroll
    for (int b = 0; b < 8; b++) acc[a][b] = 0.f;

  // ---- prologue: prefetch U for sub 0 ----
  float4 pU[8];
  {
    const int s0r = Rc * r;
    #pragma unroll
    for (int i = 0; i < 8; i++) {
      pU[i] = make_float4(0.f, 0.f, 0.f, 0.f);
      if (uoff[i] >= 0) pU[i] = *(const float4*)&u[s0r + uoff[i]];
    }
  }

  for (int sub = 0; sub < 8; sub++) {
    const int s0 = Rc + (sub << 7);
    // stage x transposed: xT[ss][n], float4 n-chunks (conflict-free b128 writes)
    #pragma unroll
    for (int rep4 = 0; rep4 < 4; rep4++) {
      const int nb = hi_st + (rep4 << 2);
      float4 v;
      v.x = x[(nb + 0) * NN + s0 + ss_st];
      v.y = x[(nb + 1) * NN + s0 + ss_st];
      v.z = x[(nb + 2) * NN + s0 + ss_st];
      v.w = x[(nb + 3) * NN + s0 + ss_st];
      *(float4*)&xT[ss_st * 36 + nb] = v;
    }
    // write prefetched U rows (swizzled; zeros already in pU for pad slots)
    #pragma unroll
    for (int i = 0; i < 8; i++)
      if (uoff[i] != -2) *(float4*)&Ut[ldso[i]] = pU[i];
    __syncthreads();

    // issue next sub's U loads: complete under this sub's FMAs
    if (sub < 7) {
      const int s1r = (s0 + 128) * r;
      #pragma unroll
      for (int i = 0; i < 8; i++) {
        if (uoff[i] >= 0) pU[i] = *(const float4*)&u[s1r + uoff[i]];
      }
    }

    if (active) {
      const int sl0 = split << 4;
      #pragma unroll 4
      for (int ss = 0; ss < 16; ss++) {
        const int sl = sl0 + ss;
        const int sx = sl & 7;
        float4 xa = *(const float4*)&xT[sl * 36 + n0];
        float4 xb = *(const float4*)&xT[sl * 36 + n0 + 4];
        float4 ua = *(const float4*)&Ut[sl * rpadS + ((qa_hi | (qa_lo ^ sx)) << 2)];
        float4 ub = *(const float4*)&Ut[sl * rpadS + ((qb_hi | (qb_lo ^ sx)) << 2)];
        float xs[8] = {xa.x, xa.y, xa.z, xa.w, xb.x, xb.y, xb.z, xb.w};
        float us[8] = {ua.x, ua.y, ua.z, ua.w, ub.x, ub.y, ub.z, ub.w};
        #pragma unroll
        for (int a = 0; a < 8; a++)
          #pragma unroll
          for (int b = 0; b < 8; b++)
            acc[a][b] += xs[a] * us[b];
      }
    }

    // block-uniform flush: end of chunk, or the 128-row window ends a segment
    const bool fl = (sub == 7) || (((s0 + 128) >> lb) != (s0 >> lb));
    if (fl) {
      __syncthreads();   // all compute reads of Ut done before reusing as scratch
      // tree-reduce across the gsz splits that share each segment
      for (int h = gsz >> 1; h >= 1; h >>= 1) {
        const int sig = split & (gsz - 1);
        if (active && sig >= h && sig < (h << 1)) {
          int rid = split - h;                         // reader split id
          int slot = (rid >> lg) * h + (rid & (gsz - 1));  // 0..3
          float* dst = Ut + slot * 2048 + lane32;      // [(a*8+b)][lane32]
          #pragma unroll
          for (int a = 0; a < 8; a++)
            #pragma unroll
            for (int b = 0; b < 8; b++)
              dst[(a * 8 + b) * 32] = acc[a][b];
        }
        __syncthreads();
        if (active && (split & (gsz - 1)) < h) {
          int slot = (split >> lg) * h + (split & (gsz - 1));
          const float* src = Ut + slot * 2048 + lane32;
          #pragma unroll
          for (int a = 0; a < 8; a++)
            #pragma unroll
            for (int b = 0; b < 8; b++)
              acc[a][b] += src[(a * 8 + b) * 32];
        }
        __syncthreads();
      }
      // group leaders write the full 32 x rpad segment tile (unique writer)
      if (active && (split & (gsz - 1)) == 0) {
        const int grow = s0 + (split << 4);
        const int gseg = grow >> lb;
        float* outp = (lb >= 10) ? (part + (l * 128 + chunk) * 2048)
                                 : (tl + gseg * 32 * rpad);
        float* base = outp + n0 * rpad + j0;
        #pragma unroll
        for (int a = 0; a < 8; a++) {
          *(float4*)&base[a * rpad]     = make_float4(acc[a][0], acc[a][1], acc[a][2], acc[a][3]);
          *(float4*)&base[a * rpad + 4] = make_float4(acc[a][4], acc[a][5], acc[a][6], acc[a][7]);
        }
      }
      #pragma unroll
      for (int a = 0; a < 8; a++)
        #pragma unroll
        for (int b = 0; b < 8; b++) acc[a][b] = 0.f;
    }
    __syncthreads();
  }
}

// ---------------- reduce: t[l][seg] = sum over chunks of part tiles (levels 0..6)
// grid: 254 blocks (one per segment), 256 threads, 8 floats each
__global__ __launch_bounds__(256)
void reduce_kernel(const float* __restrict__ part, float* __restrict__ t,
                   LevelParams P) {
  int b = blockIdx.x;
  int l = 0, segs = 2;
  while (b >= segs) { b -= segs; l++; segs <<= 1; }   // l in 0..6, b = seg index
  const int nch = 64 >> l;                            // chunks per segment
  const int tid = threadIdx.x;
  const float* src = part + (size_t)(l * 128 + b * nch) * 2048 + tid * 8;
  float s0 = 0.f, s1 = 0.f, s2 = 0.f, s3 = 0.f, s4 = 0.f, s5 = 0.f, s6 = 0.f, s7 = 0.f;
  for (int k = 0; k < nch; k++) {
    float4 v0 = *(const float4*)&src[k * 2048];
    float4 v1 = *(const float4*)&src[k * 2048 + 4];
    s0 += v0.x; s1 += v0.y; s2 += v0.z; s3 += v0.w;
    s4 += v1.x; s5 += v1.y; s6 += v1.z; s7 += v1.w;
  }
  float* dst = t + P.t_off[l] + b * 2048 + tid * 8;
  *(float4*)dst = make_float4(s0, s1, s2, s3);
  *(float4*)&dst[4] = make_float4(s4, s5, s6, s7);
}

// ---------------- y-pass: out[n][i] = leaf(i) + s2 * sum_l sum_j U_l[i][j]*t_l[sib][n][j]
// grid: N/256 WGs, 256 threads; thread tile = 8 rows x 4 batches.
// XOR-swizzled LDS (conflict-free, rounds 4-5 verified) + T14 Uc reg-prefetch:
// jc=0 loads issue before ttl staging (hide under t stage); jc+1 loads issue
// right after the top barrier (hide under jc's FMAs).
__global__ __launch_bounds__(256, 2)
void ypass_kernel(const float* __restrict__ x,
                  const float* __restrict__ leaf,
                  const float* __restrict__ scale,
                  const float* __restrict__ t,
                  float* __restrict__ out,
                  LevelParams P) {
  __shared__ float smem[13440];  // 53760 B: phase A = 9216 (xT) + 4224 (Lb chunk)
                                 //          phase B = 8192 (ttl) + 2048 (Uc)

  const int bid = blockIdx.x;
  const int tid = threadIdx.x;
  const int R0 = bid << 8;         // 256 rows per WG
  const int ig = tid >> 3;         // 0..31  -> i0l = ig*8
  const int ng = tid & 7;          // 0..7   -> n0 = ng*4
  const int i0l = ig << 3;
  const int n0 = ng << 2;

  const float sc = scale[0];
  const float s2 = sc * sc;

  float acc[8][4];
  #pragma unroll
  for (int k = 0; k < 8; k++)
    #pragma unroll
    for (int m = 0; m < 4; m++) acc[k][m] = 0.f;

  // ---- Phase A: leaf block-diagonal (leaf tile chunked 2x to halve LDS) ----
  {
    float* xT = smem;           // [256][36]
    float* Lb = smem + 9216;    // [4][32][33] = 4224 floats
    #pragma unroll 4
    for (int rep = 0; rep < 32; rep++) {
      xT[tid * 36 + rep] = x[rep * NN + R0 + tid];
    }
    const int bl = ig >> 2;           // 0..7: this thread's leaf block
    const int irow0 = (ig & 3) << 3;
    for (int ch = 0; ch < 2; ch++) {
      __syncthreads();   // xT staged (ch=0) / prev chunk compute done (ch=1)
      const float* lbase = leaf + ((R0 >> 5) + ch * 4) * 1024;
      for (int slot = tid; slot < 1024; slot += 256) {
        int flat = slot << 2;
        float4 v = *(const float4*)&lbase[flat];
        int b = flat >> 10;          // 0..3
        int tt_ = (flat >> 5) & 31;
        int s = flat & 31;
        float* dst = &Lb[b * 1056 + tt_ * 33 + s];
        dst[0] = v.x; dst[1] = v.y; dst[2] = v.z; dst[3] = v.w;
      }
      __syncthreads();
      if ((bl >> 2) == ch) {
        const int bll = bl & 3;
        #pragma unroll 4
        for (int s = 0; s < 32; s++) {
          float4 xv = *(const float4*)&xT[((bl << 5) + s) * 36 + n0];
          float xs[4] = {xv.x, xv.y, xv.z, xv.w};
          #pragma unroll
          for (int k = 0; k < 8; k++) {
            float L = Lb[bll * 1056 + (irow0 + k) * 33 + s];
            #pragma unroll
            for (int m = 0; m < 4; m++) acc[k][m] += L * xs[m];
          }
        }
      }
    }
    __syncthreads();
  }

  // ---- Phase B: levels. Sibling t staged swizzled; Uc reg-prefetched. ----
  float* ttl = smem;          // up to 8192 floats: [k][n][rpadL], quad ^= n>>2
  float* Uc  = smem + 8192;   // 2048 floats: 512 quads, quad idx ^= (slot>>4)&7
  // per-thread Uc staging constants (level-independent)
  const int slot0 = tid,       slot1 = 256 + tid;
  const int row0  = slot0 >> 1, row1 = slot1 >> 1;
  const int uch   = (tid & 1) << 2;                    // same for both reps
  const int ucq0  = (slot0 ^ ((slot0 >> 4) & 7)) << 2;
  const int ucq1  = (slot1 ^ ((slot1 >> 4) & 7)) << 2;

  for (int l = 0; l < 12; l++) {
    const float* __restrict__ u = P.u[l];
    const int r = P.r[l], rpad = P.rpad[l], lb = P.lb[l];
    const int rpadL = (r + 31) & ~31;       // 64 (r>=52), 32 (r<=32)
    const float* tl = t + P.t_off[l];
    const int segf_g = rpad << 5;           // global segment floats
    const int segf_l = rpadL << 5;          // LDS segment floats
    const int span_sh = (lb >= 8) ? 0 : (8 - lb);
    const int bseg = R0 >> lb;
    const int total4 = (segf_g << span_sh) >> 2;

    // issue Uc loads for jc=0 now: they complete under the ttl staging below
    const int ucoff0 = (R0 + row0) * r + uch;
    const int ucoff1 = (R0 + row1) * r + uch;
    float4 pv0 = make_float4(0.f, 0.f, 0.f, 0.f), pv1 = pv0;
    if (uch < r) { pv0 = *(const float4*)&u[ucoff0]; pv1 = *(const float4*)&u[ucoff1]; }

    for (int idx4 = tid; idx4 < total4; idx4 += 256) {
      int flat = idx4 << 2;
      int k, rem, n, c;
      if (rpad == 64)      { k = flat >> 11; rem = flat & 2047; n = rem >> 6; c = rem & 63; }
      else if (rpad == 32) { k = flat >> 10; rem = flat & 1023; n = rem >> 5; c = rem & 31; }
      else { k = flat / segf_g; rem = flat - k * segf_g; n = rem / rpad; c = rem - n * rpad; }
      int sib = (bseg + k) ^ 1;
      float4 v = *(const float4*)&tl[(size_t)sib * segf_g + rem];
      v.x *= s2; v.y *= s2; v.z *= s2; v.w *= s2;
      int c4s = (((c >> 2) ^ (n >> 2)) << 2);
      *(float4*)&ttl[((k << 5) | n) * rpadL + c4s] = v;
    }
    __syncthreads();
    const int kseg = i0l >> lb;   // local staged segment of this thread's rows
    const float* tt = ttl + kseg * segf_l + n0 * rpadL;
    const int nj = rpad >> 3;
    for (int jc = 0; jc < nj; jc++) {
      // write prefetched Uc (zeros already present for pad lanes)
      *(float4*)&Uc[ucq0] = pv0;
      *(float4*)&Uc[ucq1] = pv1;
      __syncthreads();
      // issue next jc's U loads: complete under this jc's FMAs
      if (jc + 1 < nj) {
        int j = ((jc + 1) << 3) + uch;
        pv0 = make_float4(0.f, 0.f, 0.f, 0.f); pv1 = pv0;
        if (j < r) {
          pv0 = *(const float4*)&u[ucoff0 + ((jc + 1) << 3)];
          pv1 = *(const float4*)&u[ucoff1 + ((jc + 1) << 3)];
        }
      }
      #pragma unroll
      for (int half = 0; half < 2; half++) {
        const int jq = (jc << 1) | half;
        const int tcol = (jq ^ ng) << 2;
        float4 tv0 = *(const float4*)&tt[0 * rpadL + tcol];
        float4 tv1 = *(const float4*)&tt[1 * rpadL + tcol];
        float4 tv2 = *(const float4*)&tt[2 * rpadL + tcol];
        float4 tv3 = *(const float4*)&tt[3 * rpadL + tcol];
        #pragma unroll
        for (int k = 0; k < 8; k++) {
          int q = ((((i0l + k) << 1) | half) ^ (ig & 7));
          float4 uv = *(const float4*)&Uc[q << 2];
          acc[k][0] += uv.x * tv0.x + uv.y * tv0.y + uv.z * tv0.z + uv.w * tv0.w;
          acc[k][1] += uv.x * tv1.x + uv.y * tv1.y + uv.z * tv1.z + uv.w * tv1.w;
          acc[k][2] += uv.x * tv2.x + uv.y * tv2.y + uv.z * tv2.z + uv.w * tv2.w;
          acc[k][3] += uv.x * tv3.x + uv.y * tv3.y + uv.z * tv3.z + uv.w * tv3.w;
        }
      }
      __syncthreads();
    }
  }

  // ---- epilogue: single write of y ----
  #pragma unroll
  for (int m = 0; m < 4; m++) {
    float4 o0 = make_float4(acc[0][m], acc[1][m], acc[2][m], acc[3][m]);
    float4 o1 = make_float4(acc[4][m], acc[5][m], acc[6][m], acc[7][m]);
    float* dst = out + (n0 + m) * NN + R0 + i0l;
    *(float4*)&dst[0] = o0;
    *(float4*)&dst[4] = o1;
  }
}

extern "C" void kernel_launch(void* const* d_in, const int* in_sizes, int n_in,
                              void* d_out, int out_size, void* d_ws, size_t ws_size,
                              hipStream_t stream) {
  const float* x     = (const float*)d_in[0];
  const float* leaf  = (const float*)d_in[1];
  const float* scale = (const float*)d_in[2];

  static const int RANKS[12] = {64,64,64,64,64,64,64,64,64,52,32,20};
  LevelParams P;
  int off = 0;
  for (int l = 0; l < 12; l++) {
    P.u[l] = (const float*)d_in[3 + l];
    P.r[l] = RANKS[l];
    P.rpad[l] = (RANKS[l] + 7) & ~7;
    P.lb[l] = 16 - l;
    P.t_off[l] = off;
    off += (2 << l) * 32 * P.rpad[l];
  }

  float* t = (float*)d_ws;
  float* part = t + off;                 // 7 levels * 128 chunks * 2048 floats

  tpass_kernel<<<dim3(12 * 128), dim3(256), 0, stream>>>(x, t, part, P);
  reduce_kernel<<<dim3(254), dim3(256), 0, stream>>>(part, t, P);
  ypass_kernel<<<dim3(NN / 256), dim3(256), 0, stream>>>(x, leaf, scale, t,
                                                         (float*)d_out, P);
}